// Round 13
// baseline (115.942 us; speedup 1.0000x reference)
//
#include <hip/hip_runtime.h>
#include <hip/hip_bf16.h>

// Problem: B=512, S=256, E=384, H=64.
// d_in: x [B,S,E] f32; Wq,Wk,Wv [E,H] f32.  d_out: [B,S,H] f32.
// ws: [0, 147456) wfrag bf16 (only region used).
//
// FUSED v13 = v12 (56.4us) + CAUSAL INTERLEAVE of attention into the proj
// loop. Attention tile rt needs only K/V/Q chunks 0..rt, which are
// LDS-visible at the top barrier of proj iter rt+1. So wave (ch-1)%12 runs
// attention tile ch-1 during proj iter ch -- inside the ~0.8us/iter slack
// where all waves stall on the staging-load vmcnt. Only tile 15 remains as
// a post-loop tail. The 10us serial attention phase collapses to ~0 exposed.
// To fit the 170-VGPR cap (3 w/SIMD) alongside the pinned af[12]=48, the
// attention body is v3's verified 2-PASS form (pass1 max / pass2 recompute
// +exp+in-lane-P+PV; no s[16] array). All other parts = v12 verbatim.

#define NB   512
#define SS   256
#define EE   384
#define HH   64

#define PR16  16            // x rows staged per chunk
#define LROW  392           // staging row stride in shorts (384 data + 8 pad)
#define XLSZ  (PR16 * LROW) // 6272 shorts per staging buffer

// lgkm-only barrier: LDS writes retired, global loads ride through (v10-verified).
#define SYNC_LDS() asm volatile("s_waitcnt lgkmcnt(0)\n\ts_barrier" ::: "memory")

typedef short bf16x8 __attribute__((ext_vector_type(8)));
typedef float f32x4  __attribute__((ext_vector_type(4)));

__device__ __forceinline__ short f2bf(float f) {
  union { float f; unsigned u; } x; x.f = f;
  unsigned r = x.u + 0x7fffu + ((x.u >> 16) & 1u);
  return (short)(r >> 16);
}

// ---------------- prep: W -> fragment-ordered bf16 (unchanged) ----------------
// wfrag[((ks*12+nf)*64 + lane)*8 + j] = Wcat[ks*32 + (lane>>4)*8 + j][nf*16 + (lane&15)]
__global__ __launch_bounds__(256) void prep_w_kernel(
    const float* __restrict__ Wq, const float* __restrict__ Wk,
    const float* __restrict__ Wv, short* __restrict__ wfrag) {
  int t = blockIdx.x * 256 + threadIdx.x;
  if (t >= 12 * 12 * 64) return;
  int ks  = t / (12 * 64);
  int rem = t % (12 * 64);
  int nf  = rem / 64;
  int l   = rem % 64;
  int l15 = l & 15, lhi = l >> 4;
  int ncat = nf * 16 + l15;
  const float* W = (ncat < 64) ? Wq : (ncat < 128 ? Wk : Wv);
  int n = ncat & 63;
  short* dst = wfrag + (size_t)t * 8;
#pragma unroll
  for (int j = 0; j < 8; ++j) {
    int kk = ks * 32 + lhi * 8 + j;
    dst[j] = f2bf(W[kk * 64 + n]);
  }
}

// ---------------- fused: one block = one batch, 12 waves, 121 KB LDS ----------------
__global__ __launch_bounds__(768, 3) void fused_kernel(
    const float* __restrict__ x, const short* __restrict__ wfrag,
    float* __restrict__ out) {
  // Ql swizzled: elem (row,h) at Ql[row*64 + (h ^ ((row&7)<<3))]       (v2..v12-verified)
  // Kl swizzled: elem (row,h) at Kl[row*64 + (h ^ (srow<<3))], srow=((row&8)>>1)|(row&3)
  // Vt swizzled: elem (h,row) at Vt[h*256 + (row ^ ((h&7)<<3))]
  // xst: dbuf of 16-row x tiles, padded stride LROW=392 (whole block cooperates)
  __shared__ __align__(16) short Ql[SS * HH];    // 32 KB
  __shared__ __align__(16) short Kl[SS * HH];    // 32 KB
  __shared__ __align__(16) short Vt[HH * SS];    // 32 KB
  __shared__ __align__(16) short xst[2 * XLSZ];  // 24.5 KB -> 123904 B total

  int b    = blockIdx.x;
  int tid  = threadIdx.x;
  int lane = tid & 63, wv = tid >> 6;            // wv in [0,12)
  int l15  = lane & 15, lhi = lane >> 4;
  int sw   = l15 & 7;
  const float* xb = x + (size_t)b * SS * EE;
  size_t obase = (size_t)b * SS * HH;

  // ---- W fragments: ONE h-tile per wave (f = wv) -> af[12] = 48 VGPR, pinned ----
  bf16x8 af[12];
#pragma unroll
  for (int ks = 0; ks < 12; ++ks)
    af[ks] = *(const bf16x8*)(wfrag + ((size_t)(ks * 12 + wv) * 64 + lane) * 8);
#pragma unroll
  for (int ks = 0; ks < 12; ++ks)
    asm volatile("" : "+v"(af[ks]));

  f32x4 st[2];
  auto loadch = [&](int ch) {  // 16 rows = 24 KB f32, 32 B/thread, fully contiguous
    const float* p0 = xb + (size_t)ch * PR16 * EE;
    const f32x4* p = (const f32x4*)(p0 + (size_t)tid * 8);
    st[0] = p[0];
    st[1] = p[1];
  };
  auto writech = [&](short* xl) {  // regs -> bf16 -> padded LDS tile, 1 store/thread
    int row = tid / 48, cg = tid % 48;   // 768 = 16 rows x 48 8-float groups
    union { bf16x8 vv; __hip_bfloat162 h2[4]; } u;
    u.h2[0] = __float22bfloat162_rn(make_float2(st[0][0], st[0][1]));
    u.h2[1] = __float22bfloat162_rn(make_float2(st[0][2], st[0][3]));
    u.h2[2] = __float22bfloat162_rn(make_float2(st[1][0], st[1][1]));
    u.h2[3] = __float22bfloat162_rn(make_float2(st[1][2], st[1][3]));
    *(bf16x8*)(xl + row * LROW + cg * 8) = u.vv;
  };

  // ---- attention tile, 2-PASS (v3-verified body, v12 mapping/swizzles) ----
  // pass1: row max (no storage). pass2: recompute scores per 32-k chunk,
  // exp in-lane, pack PA, PV MFMA. P never touches LDS or an s[] array.
  auto attn_tile = [&](int rt) {
    int qrow0 = rt * 16;
    int twp   = (rt + 2) & ~1;       // even # of interleaved 16-row k-tiles
    int nk    = twp >> 1;            // 32-k PV chunks
    int qg    = qrow0 + l15;         // this lane's q-row (P lives at q=l15)

    int qlrow = qrow0 + l15;
    bf16x8 qa0 = *(const bf16x8*)(Ql + qlrow * 64 + ((lhi * 8) ^ ((qlrow & 7) << 3)));
    bf16x8 qa1 = *(const bf16x8*)(Ql + qlrow * 64 + ((32 + lhi * 8) ^ ((qlrow & 7) << 3)));

    // pass 1: row max. tile t loads K rows kc = (t>>1)*32 + (l15>>2)*8 + (t&1)*4 + (l15&3)
    float mx = -3.0e38f;
    for (int t = 0; t < twp; ++t) {
      int kc = (t >> 1) * 32 + ((l15 >> 2) << 3) + ((t & 1) << 2) + (l15 & 3);
      const short* kp = Kl + kc * 64;
      bf16x8 kb0 = *(const bf16x8*)(kp + ((lhi * 8) ^ (sw << 3)));
      bf16x8 kb1 = *(const bf16x8*)(kp + ((32 + lhi * 8) ^ (sw << 3)));
      __builtin_amdgcn_s_setprio(1);
      f32x4 a = (f32x4){0.f, 0.f, 0.f, 0.f};
      a = __builtin_amdgcn_mfma_f32_16x16x32_bf16(kb0, qa0, a, 0, 0, 0);
      a = __builtin_amdgcn_mfma_f32_16x16x32_bf16(kb1, qa1, a, 0, 0, 0);
      __builtin_amdgcn_s_setprio(0);
#pragma unroll
      for (int r = 0; r < 4; ++r) {
        int kg = (t >> 1) * 32 + lhi * 8 + ((t & 1) << 2) + r;
        float v = a[r] * 0.125f;
        mx = (kg <= qg) ? fmaxf(mx, v) : mx;
      }
    }
    mx = fmaxf(mx, __shfl_xor(mx, 16));
    mx = fmaxf(mx, __shfl_xor(mx, 32));

    // pass 2: recompute scores, exp, accumulate sum, in-lane pa, PV
    float sm = 0.f;
    f32x4 o[4];
#pragma unroll
    for (int nf = 0; nf < 4; ++nf) o[nf] = (f32x4){0.f, 0.f, 0.f, 0.f};
    for (int kc2 = 0; kc2 < nk; ++kc2) {
      int kcA = kc2 * 32 + ((l15 >> 2) << 3) + (l15 & 3);
      const short* kpA = Kl + kcA * 64;
      const short* kpB = kpA + 4 * 64;
      bf16x8 a0 = *(const bf16x8*)(kpA + ((lhi * 8) ^ (sw << 3)));
      bf16x8 a1 = *(const bf16x8*)(kpA + ((32 + lhi * 8) ^ (sw << 3)));
      bf16x8 b0 = *(const bf16x8*)(kpB + ((lhi * 8) ^ (sw << 3)));
      bf16x8 b1 = *(const bf16x8*)(kpB + ((32 + lhi * 8) ^ (sw << 3)));
      __builtin_amdgcn_s_setprio(1);
      f32x4 aA = (f32x4){0.f, 0.f, 0.f, 0.f};
      aA = __builtin_amdgcn_mfma_f32_16x16x32_bf16(a0, qa0, aA, 0, 0, 0);
      aA = __builtin_amdgcn_mfma_f32_16x16x32_bf16(a1, qa1, aA, 0, 0, 0);
      f32x4 aB = (f32x4){0.f, 0.f, 0.f, 0.f};
      aB = __builtin_amdgcn_mfma_f32_16x16x32_bf16(b0, qa0, aB, 0, 0, 0);
      aB = __builtin_amdgcn_mfma_f32_16x16x32_bf16(b1, qa1, aB, 0, 0, 0);
      __builtin_amdgcn_s_setprio(0);
      float pA[4], pB[4];
#pragma unroll
      for (int r = 0; r < 4; ++r) {
        int kgA = kc2 * 32 + lhi * 8 + r;
        pA[r] = (kgA <= qg) ? __expf(aA[r] * 0.125f - mx) : 0.f;
        pB[r] = (kgA + 4 <= qg) ? __expf(aB[r] * 0.125f - mx) : 0.f;
        sm += pA[r] + pB[r];
      }
      union { bf16x8 v; __hip_bfloat162 h2[4]; } pu;
      pu.h2[0] = __float22bfloat162_rn(make_float2(pA[0], pA[1]));
      pu.h2[1] = __float22bfloat162_rn(make_float2(pA[2], pA[3]));
      pu.h2[2] = __float22bfloat162_rn(make_float2(pB[0], pB[1]));
      pu.h2[3] = __float22bfloat162_rn(make_float2(pB[2], pB[3]));
      int kofs = kc2 * 32 + lhi * 8;
      __builtin_amdgcn_s_setprio(1);
#pragma unroll
      for (int nf = 0; nf < 4; ++nf) {
        int hrow = nf * 16 + l15;
        bf16x8 vb = *(const bf16x8*)(Vt + hrow * 256 + (kofs ^ ((hrow & 7) << 3)));
        o[nf] = __builtin_amdgcn_mfma_f32_16x16x32_bf16(pu.v, vb, o[nf], 0, 0, 0);
      }
      __builtin_amdgcn_s_setprio(0);
    }
    sm += __shfl_xor(sm, 16);
    sm += __shfl_xor(sm, 32);
    float inv = 1.f / sm;
    float invq[4];
#pragma unroll
    for (int r = 0; r < 4; ++r) invq[r] = __shfl(inv, lhi * 4 + r);

#pragma unroll
    for (int nf = 0; nf < 4; ++nf)
#pragma unroll
      for (int r = 0; r < 4; ++r) {
        int q = qrow0 + lhi * 4 + r;
        int h = nf * 16 + l15;
        out[obase + (size_t)q * HH + h] = o[nf][r] * invq[r];
      }
  };

  // ---- projection loop with causal-interleaved attention ----
  // iter ch: chunks 0..ch-1 are LDS-visible after the top barrier; wave
  // (ch-1)%12 runs attention tile ch-1 in the staging-load slack.
  loadch(0);
  writech(xst);
  for (int ch = 0; ch < 16; ++ch) {
    if (ch < 15) loadch(ch + 1);     // next chunk's loads ride through the barrier
    SYNC_LDS();                      // LDS visible; vmcnt untouched
    const short* xl = xst + (ch & 1) * XLSZ;

    f32x4 acc = (f32x4){0.f, 0.f, 0.f, 0.f};
#pragma unroll
    for (int ks = 0; ks < 12; ++ks) {
      bf16x8 bx = *(const bf16x8*)(xl + l15 * LROW + ks * 32 + lhi * 8);
      acc = __builtin_amdgcn_mfma_f32_16x16x32_bf16(af[ks], bx, acc, 0, 0, 0);
    }

    // epilogue: f = wv (wave-uniform), ncat = wv*16 + lhi*4, row = ch*16+l15
    int row  = ch * PR16 + l15;
    int srow = ((row & 8) >> 1) | (row & 3);
    int ncat = wv * 16 + lhi * 4;
    if (wv < 4) {          // Q -> Ql, row&7 swizzle
      union { short4 s4; __hip_bfloat162 h2[2]; } oq;
      oq.h2[0] = __float22bfloat162_rn(make_float2(acc[0], acc[1]));
      oq.h2[1] = __float22bfloat162_rn(make_float2(acc[2], acc[3]));
      *(short4*)(Ql + row * 64 + (ncat ^ ((row & 7) << 3))) = oq.s4;
    } else if (wv < 8) {   // K -> Kl, srow swizzle
      int col = ncat - 64;
      union { short4 s4; __hip_bfloat162 h2[2]; } ok;
      ok.h2[0] = __float22bfloat162_rn(make_float2(acc[0], acc[1]));
      ok.h2[1] = __float22bfloat162_rn(make_float2(acc[2], acc[3]));
      *(short4*)(Kl + row * 64 + (col ^ (srow << 3))) = ok.s4;
    } else {               // V -> Vt transposed, scalar stores
#pragma unroll
      for (int j = 0; j < 4; ++j) {
        int h = ncat - 128 + j;
        Vt[h * 256 + (row ^ ((h & 7) << 3))] = f2bf(acc[j]);
      }
    }

    // interleaved attention: tile ch-1 by wave (ch-1)%12 (reads rows < ch*16
    // only -- no overlap with this iter's epilogue rows; wave-uniform branch)
    int at = ch - 1;
    if (at >= 0 && wv == (at % 12)) attn_tile(at);

    if (ch < 15) writech(xst + ((ch + 1) & 1) * XLSZ);
  }
  SYNC_LDS();                        // chunk 15 epilogue visible

  // ---- tail: only tile 15 needs chunk 15 ----
  if (wv == 3) attn_tile(15);
}

extern "C" void kernel_launch(void* const* d_in, const int* in_sizes, int n_in,
                              void* d_out, int out_size, void* d_ws, size_t ws_size,
                              hipStream_t stream) {
  const float* x  = (const float*)d_in[0];
  const float* Wq = (const float*)d_in[1];
  const float* Wk = (const float*)d_in[2];
  const float* Wv = (const float*)d_in[3];
  float* out = (float*)d_out;

  short* wfrag = (short*)d_ws;

  prep_w_kernel<<<36, 256, 0, stream>>>(Wq, Wk, Wv, wfrag);
  fused_kernel<<<512, 768, 0, stream>>>(x, wfrag, out);
}

// Round 14
// 59.551 us; speedup vs baseline: 1.9469x; 1.9469x over previous
//
#include <hip/hip_runtime.h>
#include <hip/hip_bf16.h>

// Problem: B=512, S=256, E=384, H=64.
// d_in: x [B,S,E] f32; Wq,Wk,Wv [E,H] f32.  d_out: [B,S,H] f32.
// ws: [0, 147456) wfrag bf16 (only region used).
//
// FUSED v14 = v12 (56.4us champion) + ONE change: 32-row staging chunks.
// Proj loop 16 iters -> 8 iters, barriers 17 -> 9 (v7 verified this lever
// on the 8-wave variant). Staging dbuf 24.5 -> 50 KB; LDS = 148480 B,
// still 1 block/CU at 768 threads (12 waves, occupancy unchanged). Each
// barrier window now carries 2 row-tiles of MFMA (acc[2]) -- double the
// compute cover per staging-load wait. Everything else v12 verbatim:
// af[12]=48 pinned, lgkm-only barrier, dbuf invariant, 12-wave attention.

#define NB   512
#define SS   256
#define EE   384
#define HH   64

#define PR32  32            // x rows staged per chunk
#define LROW  392           // staging row stride in shorts (384 data + 8 pad)
#define XLSZ  (PR32 * LROW) // 12544 shorts per staging buffer

// lgkm-only barrier: LDS writes retired, global loads ride through (v10-verified).
#define SYNC_LDS() asm volatile("s_waitcnt lgkmcnt(0)\n\ts_barrier" ::: "memory")

typedef short bf16x8 __attribute__((ext_vector_type(8)));
typedef float f32x4  __attribute__((ext_vector_type(4)));

__device__ __forceinline__ short f2bf(float f) {
  union { float f; unsigned u; } x; x.f = f;
  unsigned r = x.u + 0x7fffu + ((x.u >> 16) & 1u);
  return (short)(r >> 16);
}

// ---------------- prep: W -> fragment-ordered bf16 (unchanged) ----------------
// wfrag[((ks*12+nf)*64 + lane)*8 + j] = Wcat[ks*32 + (lane>>4)*8 + j][nf*16 + (lane&15)]
__global__ __launch_bounds__(256) void prep_w_kernel(
    const float* __restrict__ Wq, const float* __restrict__ Wk,
    const float* __restrict__ Wv, short* __restrict__ wfrag) {
  int t = blockIdx.x * 256 + threadIdx.x;
  if (t >= 12 * 12 * 64) return;
  int ks  = t / (12 * 64);
  int rem = t % (12 * 64);
  int nf  = rem / 64;
  int l   = rem % 64;
  int l15 = l & 15, lhi = l >> 4;
  int ncat = nf * 16 + l15;
  const float* W = (ncat < 64) ? Wq : (ncat < 128 ? Wk : Wv);
  int n = ncat & 63;
  short* dst = wfrag + (size_t)t * 8;
#pragma unroll
  for (int j = 0; j < 8; ++j) {
    int kk = ks * 32 + lhi * 8 + j;
    dst[j] = f2bf(W[kk * 64 + n]);
  }
}

// ---------------- fused: one block = one batch, 12 waves, 145 KB LDS ----------------
__global__ __launch_bounds__(768, 3) void fused_kernel(
    const float* __restrict__ x, const short* __restrict__ wfrag,
    float* __restrict__ out) {
  // Ql swizzled: elem (row,h) at Ql[row*64 + (h ^ ((row&7)<<3))]       (v2..v12-verified)
  // Kl swizzled: elem (row,h) at Kl[row*64 + (h ^ (srow<<3))], srow=((row&8)>>1)|(row&3)
  // Vt swizzled: elem (h,row) at Vt[h*256 + (row ^ ((h&7)<<3))]
  // xst: dbuf of 32-row x tiles, padded stride LROW=392 (whole block cooperates)
  __shared__ __align__(16) short Ql[SS * HH];    // 32 KB
  __shared__ __align__(16) short Kl[SS * HH];    // 32 KB
  __shared__ __align__(16) short Vt[HH * SS];    // 32 KB
  __shared__ __align__(16) short xst[2 * XLSZ];  // 50 KB -> 148480 B total

  int b    = blockIdx.x;
  int tid  = threadIdx.x;
  int lane = tid & 63, wv = tid >> 6;            // wv in [0,12)
  int l15  = lane & 15, lhi = lane >> 4;
  int sw   = l15 & 7;
  const float* xb = x + (size_t)b * SS * EE;

  // ---- W fragments: ONE h-tile per wave (f = wv) -> af[12] = 48 VGPR, pinned ----
  bf16x8 af[12];
#pragma unroll
  for (int ks = 0; ks < 12; ++ks)
    af[ks] = *(const bf16x8*)(wfrag + ((size_t)(ks * 12 + wv) * 64 + lane) * 8);
#pragma unroll
  for (int ks = 0; ks < 12; ++ks)
    asm volatile("" : "+v"(af[ks]));

  f32x4 st[4];
  auto loadch = [&](int ch) {  // 32 rows = 48 KB f32, 64 B/thread, fully contiguous
    const float* p0 = xb + (size_t)ch * PR32 * EE;
#pragma unroll
    for (int i = 0; i < 2; ++i) {
      const f32x4* p = (const f32x4*)(p0 + (size_t)(tid + 768 * i) * 8);
      st[2 * i]     = p[0];
      st[2 * i + 1] = p[1];
    }
  };
  auto writech = [&](short* xl) {  // regs -> bf16 -> padded LDS tile, 2 stores/thread
#pragma unroll
    for (int i = 0; i < 2; ++i) {
      int c = tid + 768 * i;         // 8-float group: row = c/48 (0..31), cg = c%48
      int row = c / 48, cg = c % 48;
      union { bf16x8 vv; __hip_bfloat162 h2[4]; } u;
      u.h2[0] = __float22bfloat162_rn(make_float2(st[2*i][0],   st[2*i][1]));
      u.h2[1] = __float22bfloat162_rn(make_float2(st[2*i][2],   st[2*i][3]));
      u.h2[2] = __float22bfloat162_rn(make_float2(st[2*i+1][0], st[2*i+1][1]));
      u.h2[3] = __float22bfloat162_rn(make_float2(st[2*i+1][2], st[2*i+1][3]));
      *(bf16x8*)(xl + row * LROW + cg * 8) = u.vv;
    }
  };

  // ---- projection: 8 chunks of 32 rows, dbuf, ONE lgkm-barrier per chunk ----
  // Single-barrier safety (v7/v10-verified): writech(ch+1) targets the opposite
  // buffer of the one being read; reads of that buffer happened in iteration
  // ch-1 and are retired by the barrier at iteration ch's top.
  loadch(0);
  writech(xst);
  for (int ch = 0; ch < 8; ++ch) {
    if (ch < 7) loadch(ch + 1);      // next chunk's loads ride through the barrier
    SYNC_LDS();                      // LDS visible; vmcnt untouched
    const short* xl = xst + (ch & 1) * XLSZ;

    f32x4 acc[2];
    acc[0] = (f32x4){0.f, 0.f, 0.f, 0.f};
    acc[1] = (f32x4){0.f, 0.f, 0.f, 0.f};
#pragma unroll
    for (int ks = 0; ks < 12; ++ks) {
#pragma unroll
      for (int rt = 0; rt < 2; ++rt) {
        bf16x8 bx = *(const bf16x8*)(xl + (rt * 16 + l15) * LROW + ks * 32 + lhi * 8);
        acc[rt] = __builtin_amdgcn_mfma_f32_16x16x32_bf16(af[ks], bx, acc[rt], 0, 0, 0);
      }
    }

    // epilogue: f = wv (wave-uniform), ncat = wv*16 + lhi*4, row = ch*32+rt*16+l15
    int ncat = wv * 16 + lhi * 4;
#pragma unroll
    for (int rt = 0; rt < 2; ++rt) {
      int row  = ch * PR32 + rt * 16 + l15;
      int srow = ((row & 8) >> 1) | (row & 3);
      if (wv < 4) {          // Q -> Ql, row&7 swizzle
        union { short4 s4; __hip_bfloat162 h2[2]; } oq;
        oq.h2[0] = __float22bfloat162_rn(make_float2(acc[rt][0], acc[rt][1]));
        oq.h2[1] = __float22bfloat162_rn(make_float2(acc[rt][2], acc[rt][3]));
        *(short4*)(Ql + row * 64 + (ncat ^ ((row & 7) << 3))) = oq.s4;
      } else if (wv < 8) {   // K -> Kl, srow swizzle
        int col = ncat - 64;
        union { short4 s4; __hip_bfloat162 h2[2]; } ok;
        ok.h2[0] = __float22bfloat162_rn(make_float2(acc[rt][0], acc[rt][1]));
        ok.h2[1] = __float22bfloat162_rn(make_float2(acc[rt][2], acc[rt][3]));
        *(short4*)(Kl + row * 64 + (col ^ (srow << 3))) = ok.s4;
      } else {               // V -> Vt transposed, scalar stores
#pragma unroll
        for (int j = 0; j < 4; ++j) {
          int h = ncat - 128 + j;
          Vt[h * 256 + (row ^ ((h & 7) << 3))] = f2bf(acc[rt][j]);
        }
      }
    }
    if (ch < 7) writech(xst + ((ch + 1) & 1) * XLSZ);
  }
  SYNC_LDS();                        // Ql/Kl/Vt complete (9th and last barrier)

  // ---- attention: 12-wave balanced causal partition (v6/v12-verified), in-lane P ----
  // w0:{15} w1:{14} w2:{13} w3:{12} w4:{11,0} w5:{10,1} w6:{9,2} w7:{8,3}
  // w8:{7,4} w9:{6,5} w10,w11: idle
  int nt, rt0 = 0, rt1 = 0;
  if (wv < 4)       { nt = 1; rt0 = 15 - wv; }
  else if (wv < 10) { nt = 2; rt0 = 15 - wv; rt1 = wv - 4; }
  else              { nt = 0; }

  size_t obase = (size_t)b * SS * HH;
  for (int u = 0; u < nt; ++u) {
    int rt    = (u == 0) ? rt0 : rt1;
    int qrow0 = rt * 16;
    int twp   = (rt + 2) & ~1;       // even # of interleaved 16-row k-tiles
    int nk    = twp >> 1;            // 32-k PV chunks
    int qg    = qrow0 + l15;         // this lane's q-row (P lives at q=l15)

    // Q fragments from swizzled Ql
    int qlrow = qrow0 + l15;
    bf16x8 qa0 = *(const bf16x8*)(Ql + qlrow * 64 + ((lhi * 8) ^ ((qlrow & 7) << 3)));
    bf16x8 qa1 = *(const bf16x8*)(Ql + qlrow * 64 + ((32 + lhi * 8) ^ ((qlrow & 7) << 3)));

    // scores: tile t loads K rows kc = (t>>1)*32 + (l15>>2)*8 + (t&1)*4 + (l15&3)
    // (interleaved mapping: srow(kc) == sw, and D-layout == PV A-fragment)
    f32x4 s[16];
#pragma unroll
    for (int t = 0; t < 16; ++t) {
      if (t >= twp) continue;
      int kc = (t >> 1) * 32 + ((l15 >> 2) << 3) + ((t & 1) << 2) + (l15 & 3);
      const short* kp = Kl + kc * 64;
      bf16x8 kb0 = *(const bf16x8*)(kp + ((lhi * 8) ^ (sw << 3)));
      bf16x8 kb1 = *(const bf16x8*)(kp + ((32 + lhi * 8) ^ (sw << 3)));
      __builtin_amdgcn_s_setprio(1);
      f32x4 a = (f32x4){0.f, 0.f, 0.f, 0.f};
      a = __builtin_amdgcn_mfma_f32_16x16x32_bf16(kb0, qa0, a, 0, 0, 0);
      a = __builtin_amdgcn_mfma_f32_16x16x32_bf16(kb1, qa1, a, 0, 0, 0);
      __builtin_amdgcn_s_setprio(0);
#pragma unroll
      for (int r = 0; r < 4; ++r) {
        int kg = (t >> 1) * 32 + lhi * 8 + ((t & 1) << 2) + r;
        s[t][r] = (kg <= qg) ? a[r] * 0.125f : -INFINITY;
      }
    }

    // softmax over lane-local row (q=l15), reduce across lhi groups
    float mx = -3.0e38f;
#pragma unroll
    for (int t = 0; t < 16; ++t) {
      if (t >= twp) continue;
#pragma unroll
      for (int r = 0; r < 4; ++r) mx = fmaxf(mx, s[t][r]);
    }
    mx = fmaxf(mx, __shfl_xor(mx, 16));
    mx = fmaxf(mx, __shfl_xor(mx, 32));
    float sm = 0.f;
#pragma unroll
    for (int t = 0; t < 16; ++t) {
      if (t >= twp) continue;
#pragma unroll
      for (int r = 0; r < 4; ++r) {
        float p = __expf(s[t][r] - mx);    // exp(-inf)=0
        s[t][r] = p;
        sm += p;
      }
    }
    sm += __shfl_xor(sm, 16);
    sm += __shfl_xor(sm, 32);
    float inv = 1.f / sm;
    float invq[4];
#pragma unroll
    for (int r = 0; r < 4; ++r) invq[r] = __shfl(inv, lhi * 4 + r);

    // PV: pack P in-lane (no LDS), accumulate
    f32x4 o[4];
#pragma unroll
    for (int nf = 0; nf < 4; ++nf) o[nf] = (f32x4){0.f, 0.f, 0.f, 0.f};
#pragma unroll
    for (int kc2 = 0; kc2 < 8; ++kc2) {
      if (kc2 >= nk) continue;
      union { bf16x8 v; __hip_bfloat162 h2[4]; } pu;
      pu.h2[0] = __float22bfloat162_rn(make_float2(s[2*kc2][0],   s[2*kc2][1]));
      pu.h2[1] = __float22bfloat162_rn(make_float2(s[2*kc2][2],   s[2*kc2][3]));
      pu.h2[2] = __float22bfloat162_rn(make_float2(s[2*kc2+1][0], s[2*kc2+1][1]));
      pu.h2[3] = __float22bfloat162_rn(make_float2(s[2*kc2+1][2], s[2*kc2+1][3]));
      int kofs = kc2 * 32 + lhi * 8;
      __builtin_amdgcn_s_setprio(1);
#pragma unroll
      for (int nf = 0; nf < 4; ++nf) {
        int hrow = nf * 16 + l15;
        bf16x8 vb = *(const bf16x8*)(Vt + hrow * 256 + (kofs ^ ((hrow & 7) << 3)));
        o[nf] = __builtin_amdgcn_mfma_f32_16x16x32_bf16(pu.v, vb, o[nf], 0, 0, 0);
      }
      __builtin_amdgcn_s_setprio(0);
    }

    // store (divide by row sum here)
#pragma unroll
    for (int nf = 0; nf < 4; ++nf)
#pragma unroll
      for (int r = 0; r < 4; ++r) {
        int q = qrow0 + lhi * 4 + r;
        int h = nf * 16 + l15;
        out[obase + (size_t)q * HH + h] = o[nf][r] * invq[r];
      }
  }
}

extern "C" void kernel_launch(void* const* d_in, const int* in_sizes, int n_in,
                              void* d_out, int out_size, void* d_ws, size_t ws_size,
                              hipStream_t stream) {
  const float* x  = (const float*)d_in[0];
  const float* Wq = (const float*)d_in[1];
  const float* Wk = (const float*)d_in[2];
  const float* Wv = (const float*)d_in[3];
  float* out = (float*)d_out;

  short* wfrag = (short*)d_ws;

  prep_w_kernel<<<36, 256, 0, stream>>>(Wq, Wk, Wv, wfrag);
  fused_kernel<<<512, 768, 0, stream>>>(x, wfrag, out);
}

// Round 15
// 56.853 us; speedup vs baseline: 2.0393x; 1.0475x over previous
//
#include <hip/hip_runtime.h>
#include <hip/hip_bf16.h>

// Problem: B=512, S=256, E=384, H=64.
// d_in: x [B,S,E] f32; Wq,Wk,Wv [E,H] f32.  d_out: [B,S,H] f32.
// ws: [0, 147456) wfrag bf16 (only region used).
//
// FUSED v15 = v12 RESTORED (session champion, 56.4us). Ledger:
//  - wave scaling saturated: 4w=115, 8w=57.4(v7)/57.0(v10), 12w=56.4(v12)
//  - af residency: ONLY allocator-proof form is af[12]=48 VGPR + asm pin
//    (96+ VGPR arrays demoted at >8 waves: v5/v6/v8/v11/v13)
//  - barrier halving: paid at 8 waves (v7), regressed at 12 waves (v14)
//  - phase overlap attempts (persistent v11, interleave v13): both failed
//    on allocator demotion / barrier convoying. Remaining ~15us of
//    HBM-dark attention windows is this structure's floor.

#define NB   512
#define SS   256
#define EE   384
#define HH   64

#define PR16  16            // x rows staged per chunk
#define LROW  392           // staging row stride in shorts (384 data + 8 pad)
#define XLSZ  (PR16 * LROW) // 6272 shorts per staging buffer

// lgkm-only barrier: LDS writes retired, global loads ride through (v10-verified).
#define SYNC_LDS() asm volatile("s_waitcnt lgkmcnt(0)\n\ts_barrier" ::: "memory")

typedef short bf16x8 __attribute__((ext_vector_type(8)));
typedef float f32x4  __attribute__((ext_vector_type(4)));

__device__ __forceinline__ short f2bf(float f) {
  union { float f; unsigned u; } x; x.f = f;
  unsigned r = x.u + 0x7fffu + ((x.u >> 16) & 1u);
  return (short)(r >> 16);
}

// ---------------- prep: W -> fragment-ordered bf16 (unchanged) ----------------
// wfrag[((ks*12+nf)*64 + lane)*8 + j] = Wcat[ks*32 + (lane>>4)*8 + j][nf*16 + (lane&15)]
__global__ __launch_bounds__(256) void prep_w_kernel(
    const float* __restrict__ Wq, const float* __restrict__ Wk,
    const float* __restrict__ Wv, short* __restrict__ wfrag) {
  int t = blockIdx.x * 256 + threadIdx.x;
  if (t >= 12 * 12 * 64) return;
  int ks  = t / (12 * 64);
  int rem = t % (12 * 64);
  int nf  = rem / 64;
  int l   = rem % 64;
  int l15 = l & 15, lhi = l >> 4;
  int ncat = nf * 16 + l15;
  const float* W = (ncat < 64) ? Wq : (ncat < 128 ? Wk : Wv);
  int n = ncat & 63;
  short* dst = wfrag + (size_t)t * 8;
#pragma unroll
  for (int j = 0; j < 8; ++j) {
    int kk = ks * 32 + lhi * 8 + j;
    dst[j] = f2bf(W[kk * 64 + n]);
  }
}

// ---------------- fused: one block = one batch, 12 waves, 121 KB LDS ----------------
__global__ __launch_bounds__(768, 3) void fused_kernel(
    const float* __restrict__ x, const short* __restrict__ wfrag,
    float* __restrict__ out) {
  // Ql swizzled: elem (row,h) at Ql[row*64 + (h ^ ((row&7)<<3))]       (v2..v12-verified)
  // Kl swizzled: elem (row,h) at Kl[row*64 + (h ^ (srow<<3))], srow=((row&8)>>1)|(row&3)
  // Vt swizzled: elem (h,row) at Vt[h*256 + (row ^ ((h&7)<<3))]
  // xst: dbuf of 16-row x tiles, padded stride LROW=392 (whole block cooperates)
  __shared__ __align__(16) short Ql[SS * HH];    // 32 KB
  __shared__ __align__(16) short Kl[SS * HH];    // 32 KB
  __shared__ __align__(16) short Vt[HH * SS];    // 32 KB
  __shared__ __align__(16) short xst[2 * XLSZ];  // 24.5 KB -> 123904 B total

  int b    = blockIdx.x;
  int tid  = threadIdx.x;
  int lane = tid & 63, wv = tid >> 6;            // wv in [0,12)
  int l15  = lane & 15, lhi = lane >> 4;
  int sw   = l15 & 7;
  const float* xb = x + (size_t)b * SS * EE;

  // ---- W fragments: ONE h-tile per wave (f = wv) -> af[12] = 48 VGPR, pinned ----
  bf16x8 af[12];
#pragma unroll
  for (int ks = 0; ks < 12; ++ks)
    af[ks] = *(const bf16x8*)(wfrag + ((size_t)(ks * 12 + wv) * 64 + lane) * 8);
#pragma unroll
  for (int ks = 0; ks < 12; ++ks)
    asm volatile("" : "+v"(af[ks]));

  f32x4 st[2];
  auto loadch = [&](int ch) {  // 16 rows = 24 KB f32, 32 B/thread, fully contiguous
    const float* p0 = xb + (size_t)ch * PR16 * EE;
    const f32x4* p = (const f32x4*)(p0 + (size_t)tid * 8);
    st[0] = p[0];
    st[1] = p[1];
  };
  auto writech = [&](short* xl) {  // regs -> bf16 -> padded LDS tile, 1 store/thread
    int row = tid / 48, cg = tid % 48;   // 768 = 16 rows x 48 8-float groups
    union { bf16x8 vv; __hip_bfloat162 h2[4]; } u;
    u.h2[0] = __float22bfloat162_rn(make_float2(st[0][0], st[0][1]));
    u.h2[1] = __float22bfloat162_rn(make_float2(st[0][2], st[0][3]));
    u.h2[2] = __float22bfloat162_rn(make_float2(st[1][0], st[1][1]));
    u.h2[3] = __float22bfloat162_rn(make_float2(st[1][2], st[1][3]));
    *(bf16x8*)(xl + row * LROW + cg * 8) = u.vv;
  };

  // ---- projection: 16 chunks of 16 rows, dbuf, ONE lgkm-barrier per chunk ----
  // Single-barrier safety (v7/v10-verified): writech(ch+1) targets the opposite
  // buffer of the one being read; reads of that buffer happened in iteration
  // ch-1 and are retired by the barrier at iteration ch's top.
  loadch(0);
  writech(xst);
  for (int ch = 0; ch < 16; ++ch) {
    if (ch < 15) loadch(ch + 1);     // next chunk's loads ride through the barrier
    SYNC_LDS();                      // LDS visible; vmcnt untouched
    const short* xl = xst + (ch & 1) * XLSZ;

    f32x4 acc = (f32x4){0.f, 0.f, 0.f, 0.f};
#pragma unroll
    for (int ks = 0; ks < 12; ++ks) {
      bf16x8 bx = *(const bf16x8*)(xl + l15 * LROW + ks * 32 + lhi * 8);
      acc = __builtin_amdgcn_mfma_f32_16x16x32_bf16(af[ks], bx, acc, 0, 0, 0);
    }

    // epilogue: f = wv (wave-uniform), ncat = wv*16 + lhi*4, row = ch*16+l15
    int row  = ch * PR16 + l15;
    int srow = ((row & 8) >> 1) | (row & 3);
    int ncat = wv * 16 + lhi * 4;
    if (wv < 4) {          // Q -> Ql, row&7 swizzle
      union { short4 s4; __hip_bfloat162 h2[2]; } oq;
      oq.h2[0] = __float22bfloat162_rn(make_float2(acc[0], acc[1]));
      oq.h2[1] = __float22bfloat162_rn(make_float2(acc[2], acc[3]));
      *(short4*)(Ql + row * 64 + (ncat ^ ((row & 7) << 3))) = oq.s4;
    } else if (wv < 8) {   // K -> Kl, srow swizzle
      int col = ncat - 64;
      union { short4 s4; __hip_bfloat162 h2[2]; } ok;
      ok.h2[0] = __float22bfloat162_rn(make_float2(acc[0], acc[1]));
      ok.h2[1] = __float22bfloat162_rn(make_float2(acc[2], acc[3]));
      *(short4*)(Kl + row * 64 + (col ^ (srow << 3))) = ok.s4;
    } else {               // V -> Vt transposed, scalar stores
#pragma unroll
      for (int j = 0; j < 4; ++j) {
        int h = ncat - 128 + j;
        Vt[h * 256 + (row ^ ((h & 7) << 3))] = f2bf(acc[j]);
      }
    }
    if (ch < 15) writech(xst + ((ch + 1) & 1) * XLSZ);
  }
  SYNC_LDS();                        // Ql/Kl/Vt complete (17th and last barrier)

  // ---- attention: 12-wave balanced causal partition (v6-verified), in-lane P ----
  // w0:{15} w1:{14} w2:{13} w3:{12} w4:{11,0} w5:{10,1} w6:{9,2} w7:{8,3}
  // w8:{7,4} w9:{6,5} w10,w11: idle
  int nt, rt0 = 0, rt1 = 0;
  if (wv < 4)       { nt = 1; rt0 = 15 - wv; }
  else if (wv < 10) { nt = 2; rt0 = 15 - wv; rt1 = wv - 4; }
  else              { nt = 0; }

  size_t obase = (size_t)b * SS * HH;
  for (int u = 0; u < nt; ++u) {
    int rt    = (u == 0) ? rt0 : rt1;
    int qrow0 = rt * 16;
    int twp   = (rt + 2) & ~1;       // even # of interleaved 16-row k-tiles
    int nk    = twp >> 1;            // 32-k PV chunks
    int qg    = qrow0 + l15;         // this lane's q-row (P lives at q=l15)

    // Q fragments from swizzled Ql
    int qlrow = qrow0 + l15;
    bf16x8 qa0 = *(const bf16x8*)(Ql + qlrow * 64 + ((lhi * 8) ^ ((qlrow & 7) << 3)));
    bf16x8 qa1 = *(const bf16x8*)(Ql + qlrow * 64 + ((32 + lhi * 8) ^ ((qlrow & 7) << 3)));

    // scores: tile t loads K rows kc = (t>>1)*32 + (l15>>2)*8 + (t&1)*4 + (l15&3)
    // (interleaved mapping: srow(kc) == sw, and D-layout == PV A-fragment)
    f32x4 s[16];
#pragma unroll
    for (int t = 0; t < 16; ++t) {
      if (t >= twp) continue;
      int kc = (t >> 1) * 32 + ((l15 >> 2) << 3) + ((t & 1) << 2) + (l15 & 3);
      const short* kp = Kl + kc * 64;
      bf16x8 kb0 = *(const bf16x8*)(kp + ((lhi * 8) ^ (sw << 3)));
      bf16x8 kb1 = *(const bf16x8*)(kp + ((32 + lhi * 8) ^ (sw << 3)));
      __builtin_amdgcn_s_setprio(1);
      f32x4 a = (f32x4){0.f, 0.f, 0.f, 0.f};
      a = __builtin_amdgcn_mfma_f32_16x16x32_bf16(kb0, qa0, a, 0, 0, 0);
      a = __builtin_amdgcn_mfma_f32_16x16x32_bf16(kb1, qa1, a, 0, 0, 0);
      __builtin_amdgcn_s_setprio(0);
#pragma unroll
      for (int r = 0; r < 4; ++r) {
        int kg = (t >> 1) * 32 + lhi * 8 + ((t & 1) << 2) + r;
        s[t][r] = (kg <= qg) ? a[r] * 0.125f : -INFINITY;
      }
    }

    // softmax over lane-local row (q=l15), reduce across lhi groups
    float mx = -3.0e38f;
#pragma unroll
    for (int t = 0; t < 16; ++t) {
      if (t >= twp) continue;
#pragma unroll
      for (int r = 0; r < 4; ++r) mx = fmaxf(mx, s[t][r]);
    }
    mx = fmaxf(mx, __shfl_xor(mx, 16));
    mx = fmaxf(mx, __shfl_xor(mx, 32));
    float sm = 0.f;
#pragma unroll
    for (int t = 0; t < 16; ++t) {
      if (t >= twp) continue;
#pragma unroll
      for (int r = 0; r < 4; ++r) {
        float p = __expf(s[t][r] - mx);    // exp(-inf)=0
        s[t][r] = p;
        sm += p;
      }
    }
    sm += __shfl_xor(sm, 16);
    sm += __shfl_xor(sm, 32);
    float inv = 1.f / sm;
    float invq[4];
#pragma unroll
    for (int r = 0; r < 4; ++r) invq[r] = __shfl(inv, lhi * 4 + r);

    // PV: pack P in-lane (no LDS), accumulate
    f32x4 o[4];
#pragma unroll
    for (int nf = 0; nf < 4; ++nf) o[nf] = (f32x4){0.f, 0.f, 0.f, 0.f};
#pragma unroll
    for (int kc2 = 0; kc2 < 8; ++kc2) {
      if (kc2 >= nk) continue;
      union { bf16x8 v; __hip_bfloat162 h2[4]; } pu;
      pu.h2[0] = __float22bfloat162_rn(make_float2(s[2*kc2][0],   s[2*kc2][1]));
      pu.h2[1] = __float22bfloat162_rn(make_float2(s[2*kc2][2],   s[2*kc2][3]));
      pu.h2[2] = __float22bfloat162_rn(make_float2(s[2*kc2+1][0], s[2*kc2+1][1]));
      pu.h2[3] = __float22bfloat162_rn(make_float2(s[2*kc2+1][2], s[2*kc2+1][3]));
      int kofs = kc2 * 32 + lhi * 8;
      __builtin_amdgcn_s_setprio(1);
#pragma unroll
      for (int nf = 0; nf < 4; ++nf) {
        int hrow = nf * 16 + l15;
        bf16x8 vb = *(const bf16x8*)(Vt + hrow * 256 + (kofs ^ ((hrow & 7) << 3)));
        o[nf] = __builtin_amdgcn_mfma_f32_16x16x32_bf16(pu.v, vb, o[nf], 0, 0, 0);
      }
      __builtin_amdgcn_s_setprio(0);
    }

    // store (divide by row sum here)
#pragma unroll
    for (int nf = 0; nf < 4; ++nf)
#pragma unroll
      for (int r = 0; r < 4; ++r) {
        int q = qrow0 + lhi * 4 + r;
        int h = nf * 16 + l15;
        out[obase + (size_t)q * HH + h] = o[nf][r] * invq[r];
      }
  }
}

extern "C" void kernel_launch(void* const* d_in, const int* in_sizes, int n_in,
                              void* d_out, int out_size, void* d_ws, size_t ws_size,
                              hipStream_t stream) {
  const float* x  = (const float*)d_in[0];
  const float* Wq = (const float*)d_in[1];
  const float* Wk = (const float*)d_in[2];
  const float* Wv = (const float*)d_in[3];
  float* out = (float*)d_out;

  short* wfrag = (short*)d_ws;

  prep_w_kernel<<<36, 256, 0, stream>>>(Wq, Wk, Wv, wfrag);
  fused_kernel<<<512, 768, 0, stream>>>(x, wfrag, out);
}